// Round 5
// baseline (162.266 us; speedup 1.0000x reference)
//
#include <hip/hip_runtime.h>

namespace {
constexpr int Bn = 4096;
constexpr int Ln = 2048;
constexpr float TAU = 0.85f;
constexpr float MARGIN = 0.0005f;
constexpr float RW = 0.5f;
constexpr float CW = 0.5f;

constexpr int ROWS_PER_BLOCK = 4;   // one wave (64 lanes) per row, no barriers
constexpr int EPL = Ln / 64;        // 32 elements per lane
static_assert(EPL == 32, "layout assumption");

// One WAVE per row: 64 lanes x 32 elems. Zero __syncthreads, zero LDS.
// All reductions are wave-local shfl; T broadcast via shfl from lane 63.
// r = 2c/(k+T) in [0,1] => z = r/TAU <= 1.18: no max-subtraction needed.
// sum q*log q folded algebraically: t1/esum - log(esum).
__global__ __launch_bounds__(256) void mt_row_kernel(
    const float* __restrict__ pred,
    const float* __restrict__ rerank,
    const float* __restrict__ cut,
    const float* __restrict__ labels,
    float* __restrict__ part)
{
  const int tid  = threadIdx.x;
  const int lane = tid & 63;
  const int wid  = tid >> 6;
  const int row  = blockIdx.x * ROWS_PER_BLOCK + wid;
  const size_t base = (size_t)row * Ln + (size_t)lane * EPL;

  // ---- labels ----
  float A[EPL];                       // labels -> prefix -> exp values (in place)
  #pragma unroll
  for (int c = 0; c < 8; ++c) {
    const float4 v = reinterpret_cast<const float4*>(labels + base)[c];
    A[4*c+0] = v.x; A[4*c+1] = v.y; A[4*c+2] = v.z; A[4*c+3] = v.w;
  }
  // ---- pred / rerank: consumed immediately into scalars ----
  float Y[EPL];
  #pragma unroll
  for (int c = 0; c < 8; ++c) {
    const float4 v = reinterpret_cast<const float4*>(pred + base)[c];
    Y[4*c+0] = v.x; Y[4*c+1] = v.y; Y[4*c+2] = v.z; Y[4*c+3] = v.w;
  }
  float S[EPL];
  #pragma unroll
  for (int c = 0; c < 8; ++c) {
    const float4 v = reinterpret_cast<const float4*>(rerank + base)[c];
    S[4*c+0] = v.x; S[4*c+1] = v.y; S[4*c+2] = v.z; S[4*c+3] = v.w;
  }

  float bce = 0.f, s_all = 0.f, s_pos = 0.f;
  #pragma unroll
  for (int j = 0; j < EPL; ++j) {
    const float x = (A[j] == 1.f) ? Y[j] : (1.f - Y[j]);
    bce   += __logf(x);
    s_all += S[j];
    s_pos += S[j] * A[j];
  }

  // ---- issue cut loads now (in flight during the scan) ----
  float P[EPL];
  #pragma unroll
  for (int c = 0; c < 8; ++c) {
    const float4 v = reinterpret_cast<const float4*>(cut + base)[c];
    P[4*c+0] = v.x; P[4*c+1] = v.y; P[4*c+2] = v.z; P[4*c+3] = v.w;
  }

  // ---- in-lane inclusive prefix of labels (exact small ints) ----
  float run = 0.f;
  #pragma unroll
  for (int j = 0; j < EPL; ++j) { run += A[j]; A[j] = run; }
  const float own = run;

  // ---- wave scan of per-lane totals ----
  float sc = own;
  #pragma unroll
  for (int off = 1; off < 64; off <<= 1) {
    const float n = __shfl_up(sc, off, 64);
    if (lane >= off) sc += n;
  }
  const float T    = __shfl(sc, 63, 64);   // row total
  const float excl = sc - own;             // exclusive prefix for this lane

  // ---- z = (2c/(k+T))/TAU in [0,1.18]; accumulate esum, sum e*z ----
  float esum = 0.f, t1 = 0.f;
  const float kT = T;
  const float kbase = (float)(lane * EPL);
  #pragma unroll
  for (int j = 0; j < EPL; ++j) {
    const float c = excl + A[j];
    const float k = kbase + (float)(j + 1);
    const float z = __fdividef(2.f * c, (k + kT) * TAU);
    const float ev = __expf(z);
    A[j] = ev;                             // overwrite prefix with exp value
    esum += ev;
    t1   += ev * z;
  }
  #pragma unroll
  for (int off = 32; off > 0; off >>= 1) {
    esum += __shfl_xor(esum, off, 64);
    t1   += __shfl_xor(t1,   off, 64);
  }
  const float inv = 1.f / esum;

  // ---- KL vs cut_y: kl_row = t1/esum - log esum + sum[p logp - (p+q) log((p+q)/2)] ----
  float kl = 0.f;
  #pragma unroll
  for (int j = 0; j < EPL; ++j) {
    const float q  = A[j] * inv;
    const float pq = P[j] + q;
    kl += P[j] * __logf(P[j]) - pq * __logf(pq * 0.5f);
  }

  // ---- wave-reduce 4 scalars (independent, pipelined) ----
  #pragma unroll
  for (int off = 32; off > 0; off >>= 1) {
    kl    += __shfl_xor(kl,    off, 64);
    s_all += __shfl_xor(s_all, off, 64);
    s_pos += __shfl_xor(s_pos, off, 64);
    bce   += __shfl_xor(bce,   off, 64);
  }
  if (lane == 0) {
    part[0 * Bn + row] = kl + t1 * inv - __logf(esum);
    part[1 * Bn + row] = s_all;
    part[2 * Bn + row] = s_pos;
    part[3 * Bn + row] = bce;
    part[4 * Bn + row] = T;
  }
}

// Single block: reduce 4096 per-row partials in double, emit scalar.
__global__ __launch_bounds__(256) void mt_final_kernel(
    const float* __restrict__ part, float* __restrict__ out)
{
  const int tid  = threadIdx.x;
  const int lane = tid & 63;
  const int wid  = tid >> 6;
  double kl = 0, sv = 0, sp = 0, bc = 0, tt = 0;
  for (int r = tid; r < Bn; r += 256) {
    kl += (double)part[0 * Bn + r];
    sv += (double)part[1 * Bn + r];
    sp += (double)part[2 * Bn + r];
    bc += (double)part[3 * Bn + r];
    tt += (double)part[4 * Bn + r];
  }
  #pragma unroll
  for (int off = 32; off > 0; off >>= 1) {
    kl += __shfl_xor(kl, off, 64);
    sv += __shfl_xor(sv, off, 64);
    sp += __shfl_xor(sp, off, 64);
    bc += __shfl_xor(bc, off, 64);
    tt += __shfl_xor(tt, off, 64);
  }
  __shared__ double sh[4][5];
  if (lane == 0) { sh[wid][0] = kl; sh[wid][1] = sv; sh[wid][2] = sp; sh[wid][3] = bc; sh[wid][4] = tt; }
  __syncthreads();
  if (tid == 0) {
    kl = sh[0][0] + sh[1][0] + sh[2][0] + sh[3][0];
    sv = sh[0][1] + sh[1][1] + sh[2][1] + sh[3][1];
    sp = sh[0][2] + sh[1][2] + sh[2][2] + sh[3][2];
    bc = sh[0][3] + sh[1][3] + sh[2][3] + sh[3][3];
    tt = sh[0][4] + sh[1][4] + sh[2][4] + sh[3][4];
    const double total = (double)Bn * (double)Ln;
    const double posc = tt, negc = total - tt;
    double rer = (sv - sp) / negc - sp / posc + (double)MARGIN;  // neg_mean - pos_mean + margin
    if (rer < 0.0) rer = 0.0;
    rer *= (double)RW;
    const double cutl = 0.5 * kl / (double)Bn;
    const double bcel = -(bc / total) * (double)CW;
    out[0] = (float)(cutl + rer + bcel);
  }
}
} // namespace

extern "C" void kernel_launch(void* const* d_in, const int* in_sizes, int n_in,
                              void* d_out, int out_size, void* d_ws, size_t ws_size,
                              hipStream_t stream) {
  const float* pred   = (const float*)d_in[0];  // pred_y   (B,L,1)
  const float* rerank = (const float*)d_in[1];  // rerank_y (B,L,1)
  const float* cut    = (const float*)d_in[2];  // cut_y    (B,L,1)
  const float* labels = (const float*)d_in[3];  // labels   (B,L)
  float* part = (float*)d_ws;                   // 5 * Bn floats = 80 KB
  mt_row_kernel<<<Bn / ROWS_PER_BLOCK, 256, 0, stream>>>(pred, rerank, cut, labels, part);
  mt_final_kernel<<<1, 256, 0, stream>>>(part, (float*)d_out);
}

// Round 6
// 156.281 us; speedup vs baseline: 1.0383x; 1.0383x over previous
//
#include <hip/hip_runtime.h>

namespace {
constexpr int Bn = 4096;
constexpr int Ln = 2048;
constexpr float TAU = 0.85f;
constexpr float MARGIN = 0.0005f;
constexpr float RW = 0.5f;
constexpr float CW = 0.5f;

constexpr int THREADS = 256;   // 4 waves; 8 elems/thread covers L=2048
constexpr int EPT = Ln / THREADS;
static_assert(EPT == 8, "layout assumption");

typedef float f32x4 __attribute__((ext_vector_type(4)));

// One block per row, EPT=8 (R4 structure — best measured, no spills).
// NEW: all 8 global dwordx4 loads are pinned in-flight via an asm "v"-use
// + sched_barrier(0), so the scheduler cannot re-sink them to first use
// (R4 showed VGPR=32 => loads were serialized into 4 latency exposures).
__global__ __launch_bounds__(THREADS) void mt_row_kernel(
    const float* __restrict__ pred,
    const float* __restrict__ rerank,
    const float* __restrict__ cut,
    const float* __restrict__ labels,
    float* __restrict__ part)
{
  const int row  = blockIdx.x;
  const int tid  = threadIdx.x;
  const int lane = tid & 63;
  const int wid  = tid >> 6;
  const size_t base = (size_t)row * Ln + (size_t)tid * EPT;

  __shared__ float wtot[4];
  __shared__ float smid[4][2];
  __shared__ float sacc[4][4];

  // ---- ALL global loads issued up front and PINNED ----
  const f32x4 la = *(const f32x4*)(labels + base);
  const f32x4 lb = *(const f32x4*)(labels + base + 4);
  const f32x4 ya = *(const f32x4*)(pred   + base);
  const f32x4 yb = *(const f32x4*)(pred   + base + 4);
  const f32x4 sa = *(const f32x4*)(rerank + base);
  const f32x4 sb = *(const f32x4*)(rerank + base + 4);
  const f32x4 pa = *(const f32x4*)(cut    + base);
  const f32x4 pb = *(const f32x4*)(cut    + base + 4);
  asm volatile("" :: "v"(la), "v"(lb), "v"(ya), "v"(yb),
                     "v"(sa), "v"(sb), "v"(pa), "v"(pb));
  __builtin_amdgcn_sched_barrier(0);

  const float lab[8] = {la[0], la[1], la[2], la[3], lb[0], lb[1], lb[2], lb[3]};
  const float y[8]   = {ya[0], ya[1], ya[2], ya[3], yb[0], yb[1], yb[2], yb[3]};
  const float sv[8]  = {sa[0], sa[1], sa[2], sa[3], sb[0], sb[1], sb[2], sb[3]};
  const float p[8]   = {pa[0], pa[1], pa[2], pa[3], pb[0], pb[1], pb[2], pb[3]};

  // ---- independent sums first: BCE, rerank, sum p*log p ----
  float bce = 0.f, s_all = 0.f, s_pos = 0.f, plp = 0.f;
  #pragma unroll
  for (int j = 0; j < 8; ++j) {
    const float x = (lab[j] == 1.f) ? y[j] : (1.f - y[j]);
    bce   += __logf(x);
    s_all += sv[j];
    s_pos += sv[j] * lab[j];
    plp   += p[j] * __logf(p[j]);
  }

  // ---- thread-local label prefix + wave scan (exact small ints) ----
  float pref[8];
  float run = 0.f;
  #pragma unroll
  for (int j = 0; j < 8; ++j) { run += lab[j]; pref[j] = run; }
  const float own = run;
  float sc = own;
  #pragma unroll
  for (int off = 1; off < 64; off <<= 1) {
    float n = __shfl_up(sc, off, 64);
    if (lane >= off) sc += n;
  }
  if (lane == 63) wtot[wid] = sc;
  __syncthreads();
  float woff = 0.f;
  #pragma unroll
  for (int w = 0; w < 4; ++w) if (w < wid) woff += wtot[w];
  const float T = wtot[0] + wtot[1] + wtot[2] + wtot[3];
  const float excl = woff + sc - own;   // exclusive prefix for this thread

  // ---- z = (2c/(k+T))/TAU in [0,1.18]: exp w/o max-sub; accumulate e, e*z ----
  float e[8];
  float esum = 0.f, t1 = 0.f;
  const float kbase = (float)(tid * EPT);
  #pragma unroll
  for (int j = 0; j < 8; ++j) {
    const float c = excl + pref[j];
    const float k = kbase + (float)(j + 1);
    const float z = __fdividef(2.f * c, (k + T) * TAU);
    const float ev = __expf(z);
    e[j] = ev;
    esum += ev;
    t1   += ev * z;
  }
  #pragma unroll
  for (int off = 32; off > 0; off >>= 1) {
    esum += __shfl_xor(esum, off, 64);
    t1   += __shfl_xor(t1,   off, 64);
  }
  if (lane == 0) { smid[wid][0] = esum; smid[wid][1] = t1; }
  __syncthreads();
  esum = smid[0][0] + smid[1][0] + smid[2][0] + smid[3][0];
  t1   = smid[0][1] + smid[1][1] + smid[2][1] + smid[3][1];
  const float inv = 1.f / esum;

  // ---- late KL part: only log((p+q)/2) remains transcendental ----
  float kl = plp;
  #pragma unroll
  for (int j = 0; j < 8; ++j) {
    const float q  = e[j] * inv;
    const float lm = __logf((p[j] + q) * 0.5f);
    kl -= (p[j] + q) * lm;
  }

  // ---- block-reduce 4 scalars ----
  #pragma unroll
  for (int off = 32; off > 0; off >>= 1) {
    kl    += __shfl_xor(kl,    off, 64);
    s_all += __shfl_xor(s_all, off, 64);
    s_pos += __shfl_xor(s_pos, off, 64);
    bce   += __shfl_xor(bce,   off, 64);
  }
  if (lane == 0) { sacc[wid][0] = kl; sacc[wid][1] = s_all; sacc[wid][2] = s_pos; sacc[wid][3] = bce; }
  __syncthreads();
  if (tid == 0) {
    const float klrow = sacc[0][0] + sacc[1][0] + sacc[2][0] + sacc[3][0]
                      + t1 * inv - __logf(esum);
    part[0 * Bn + row] = klrow;
    part[1 * Bn + row] = sacc[0][1] + sacc[1][1] + sacc[2][1] + sacc[3][1];
    part[2 * Bn + row] = sacc[0][2] + sacc[1][2] + sacc[2][2] + sacc[3][2];
    part[3 * Bn + row] = sacc[0][3] + sacc[1][3] + sacc[2][3] + sacc[3][3];
    part[4 * Bn + row] = T;
  }
}

// Single block: reduce 4096 per-row partials in double, emit scalar.
__global__ __launch_bounds__(256) void mt_final_kernel(
    const float* __restrict__ part, float* __restrict__ out)
{
  const int tid  = threadIdx.x;
  const int lane = tid & 63;
  const int wid  = tid >> 6;
  double kl = 0, sv = 0, sp = 0, bc = 0, tt = 0;
  for (int r = tid; r < Bn; r += 256) {
    kl += (double)part[0 * Bn + r];
    sv += (double)part[1 * Bn + r];
    sp += (double)part[2 * Bn + r];
    bc += (double)part[3 * Bn + r];
    tt += (double)part[4 * Bn + r];
  }
  #pragma unroll
  for (int off = 32; off > 0; off >>= 1) {
    kl += __shfl_xor(kl, off, 64);
    sv += __shfl_xor(sv, off, 64);
    sp += __shfl_xor(sp, off, 64);
    bc += __shfl_xor(bc, off, 64);
    tt += __shfl_xor(tt, off, 64);
  }
  __shared__ double sh[4][5];
  if (lane == 0) { sh[wid][0] = kl; sh[wid][1] = sv; sh[wid][2] = sp; sh[wid][3] = bc; sh[wid][4] = tt; }
  __syncthreads();
  if (tid == 0) {
    kl = sh[0][0] + sh[1][0] + sh[2][0] + sh[3][0];
    sv = sh[0][1] + sh[1][1] + sh[2][1] + sh[3][1];
    sp = sh[0][2] + sh[1][2] + sh[2][2] + sh[3][2];
    bc = sh[0][3] + sh[1][3] + sh[2][3] + sh[3][3];
    tt = sh[0][4] + sh[1][4] + sh[2][4] + sh[3][4];
    const double total = (double)Bn * (double)Ln;
    const double posc = tt, negc = total - tt;
    double rer = (sv - sp) / negc - sp / posc + (double)MARGIN;  // neg_mean - pos_mean + margin
    if (rer < 0.0) rer = 0.0;
    rer *= (double)RW;
    const double cutl = 0.5 * kl / (double)Bn;
    const double bcel = -(bc / total) * (double)CW;
    out[0] = (float)(cutl + rer + bcel);
  }
}
} // namespace

extern "C" void kernel_launch(void* const* d_in, const int* in_sizes, int n_in,
                              void* d_out, int out_size, void* d_ws, size_t ws_size,
                              hipStream_t stream) {
  const float* pred   = (const float*)d_in[0];  // pred_y   (B,L,1)
  const float* rerank = (const float*)d_in[1];  // rerank_y (B,L,1)
  const float* cut    = (const float*)d_in[2];  // cut_y    (B,L,1)
  const float* labels = (const float*)d_in[3];  // labels   (B,L)
  float* part = (float*)d_ws;                   // 5 * Bn floats = 80 KB
  mt_row_kernel<<<Bn, THREADS, 0, stream>>>(pred, rerank, cut, labels, part);
  mt_final_kernel<<<1, 256, 0, stream>>>(part, (float*)d_out);
}